// Round 2
// baseline (1401.723 us; speedup 1.0000x reference)
//
#include <hip/hip_runtime.h>
#include <hip/hip_cooperative_groups.h>
#include <cstdint>

namespace cg = cooperative_groups;

#define N_NODES 100000
#define N_EDGES 1600000
#define ETOT    1700000   // edges + self loops
#define FIN     512
#define HD1     64        // 8 heads * 8 dims
#define C2      40
#define NEG_SLOPE 0.2f

#define BLOCK_T  512      // 8 waves
#define NCH      196      // ceil(N_NODES/512) scan chunks
#define GTILES   782      // ceil(N_NODES/128) gemm tiles

typedef __attribute__((ext_vector_type(8))) short bf16x8;
typedef __attribute__((ext_vector_type(4))) float f32x4;

struct GArgs {
    const float* x; const int* ei;
    const float* W1; const float* a_s1; const float* a_d1; const float* b1;
    const float* W2; const float* a_s2; const float* a_d2; const float* b2;
    float* out; float* ws;
};

__device__ __forceinline__ float lrelu(float v) { return v > 0.f ? v : NEG_SLOPE * v; }

__device__ __forceinline__ unsigned short f2bf(float f) {
    uint32_t u = __float_as_uint(f);
    u += 0x7FFF + ((u >> 16) & 1);   // round-to-nearest-even
    return (unsigned short)(u >> 16);
}
__device__ __forceinline__ float bf2f(unsigned short u) {
    return __uint_as_float(((uint32_t)u) << 16);
}

// workspace layout (float-element offsets), non-overlapping (ws is ~800 MB):
#define WS_PTRS(ws_)                                              \
    unsigned short* h1b = (unsigned short*)(ws_);                 \
    float* as1 = (ws_) + 3200000;                                 \
    float* ad1 = (ws_) + 4000000;                                 \
    unsigned short* hb  = (unsigned short*)((ws_) + 4800000);     \
    unsigned short* h2b = (unsigned short*)((ws_) + 8000000);     \
    float* as2 = (ws_) + 10000000;                                \
    float* ad2 = (ws_) + 10100000;                                \
    unsigned short* W1t = (unsigned short*)((ws_) + 10200000);    \
    unsigned short* W2t = (unsigned short*)((ws_) + 10250000);    \
    int* row_ptr = (int*)((ws_) + 10300000);                      \
    int* deg     = (int*)((ws_) + 10410000);                      \
    int* ord     = (int*)((ws_) + 10520000);                      \
    int* csr_src = (int*)((ws_) + 12250000);                      \
    int* bsum    = (int*)((ws_) + 13960000);                      \
    int* boff    = (int*)((ws_) + 13970000);                      \
    (void)h1b; (void)as1; (void)ad1; (void)hb; (void)h2b;         \
    (void)as2; (void)ad2; (void)W1t; (void)W2t; (void)row_ptr;    \
    (void)deg; (void)ord; (void)csr_src; (void)bsum; (void)boff;

// ================= P0: zero deg; prep W1t / W2t =================
__device__ void phase0(const GArgs& g) {
    WS_PTRS(g.ws);
    const int NTH = gridDim.x * BLOCK_T;
    const int tg  = blockIdx.x * BLOCK_T + threadIdx.x;
    for (int i = tg; i < N_NODES; i += NTH) deg[i] = 0;
    for (int i = tg; i < 80 * 512 + 48 * 64; i += NTH) {
        if (i < 80 * 512) {
            int n = i >> 9, k = i & 511;
            float v;
            if (n < 64) {
                v = g.W1[k * HD1 + n];
            } else if (n < 72) {
                int h = n - 64; v = 0.f;
#pragma unroll
                for (int d = 0; d < 8; d++) v += g.W1[k * HD1 + h * 8 + d] * g.a_s1[h * 8 + d];
            } else {
                int h = n - 72; v = 0.f;
#pragma unroll
                for (int d = 0; d < 8; d++) v += g.W1[k * HD1 + h * 8 + d] * g.a_d1[h * 8 + d];
            }
            W1t[n * FIN + k] = f2bf(v);
        } else {
            int j = i - 80 * 512;
            int n = j >> 6, k = j & 63;
            float v = 0.f;
            if (n < C2) {
                v = g.W2[k * C2 + n];
            } else if (n == C2) {
                for (int c = 0; c < C2; c++) v += g.W2[k * C2 + c] * g.a_s2[c];
            } else if (n == C2 + 1) {
                for (int c = 0; c < C2; c++) v += g.W2[k * C2 + c] * g.a_d2[c];
            }
            W2t[n * 64 + k] = f2bf(v);
        }
    }
}

// ================= P1: degrees + per-edge rank (single atomic pass) =================
__device__ void phase1(const GArgs& g) {
    WS_PTRS(g.ws);
    const int NTH = gridDim.x * BLOCK_T;
    const int tg  = blockIdx.x * BLOCK_T + threadIdx.x;
    for (int e = tg; e < ETOT; e += NTH) {
        int dst = (e < N_EDGES) ? g.ei[N_EDGES + e] : e - N_EDGES;
        ord[e] = atomicAdd(&deg[dst], 1);
    }
}

// ================= P2: per-chunk (512) scan -> row_ptr partial, bsum =================
__device__ void phase2(const GArgs& g) {
    WS_PTRS(g.ws);
    __shared__ int sc[512];
    const int t = threadIdx.x;
    for (int ch = blockIdx.x; ch < NCH; ch += gridDim.x) {
        int base = ch << 9;
        int i = base + t;
        int v = (i < N_NODES) ? deg[i] : 0;
        sc[t] = v;
        __syncthreads();
        for (int off = 1; off < 512; off <<= 1) {
            int u = (t >= off) ? sc[t - off] : 0;
            __syncthreads();
            sc[t] += u;
            __syncthreads();
        }
        if (i < N_NODES) row_ptr[i] = sc[t] - v;   // chunk-local exclusive
        if (t == 511) bsum[ch] = sc[511];
        __syncthreads();
    }
}

// ================= P3: scan of chunk sums (block 0) =================
__device__ void phase3(const GArgs& g) {
    WS_PTRS(g.ws);
    if (blockIdx.x != 0) return;
    __shared__ int sc[512];
    const int t = threadIdx.x;
    int v = (t < NCH) ? bsum[t] : 0;
    sc[t] = v;
    __syncthreads();
    for (int off = 1; off < 512; off <<= 1) {
        int u = (t >= off) ? sc[t - off] : 0;
        __syncthreads();
        sc[t] += u;
        __syncthreads();
    }
    if (t < NCH) boff[t] = sc[t] - v;   // exclusive
}

// ================= P4: finalize row_ptr =================
__device__ void phase4(const GArgs& g) {
    WS_PTRS(g.ws);
    const int NTH = gridDim.x * BLOCK_T;
    const int tg  = blockIdx.x * BLOCK_T + threadIdx.x;
    for (int i = tg; i < N_NODES; i += NTH) row_ptr[i] += boff[i >> 9];
    if (tg == 0) row_ptr[N_NODES] = ETOT;
}

// ---- gemm1 one 128-row tile (8 waves, 1 m-subtile each; N=80 = 5 n-tiles) ----
__device__ __forceinline__ void gemm1_tile(const GArgs& g, unsigned short* As, int row0) {
    WS_PTRS(g.ws);
    const int t = threadIdx.x, lane = t & 63, wv = t >> 6;
    const int quad = lane >> 4, l16 = lane & 15;

    f32x4 acc[5];
#pragma unroll
    for (int ni = 0; ni < 5; ni++) acc[ni] = (f32x4){0.f, 0.f, 0.f, 0.f};

    float4 rx[4];
#pragma unroll
    for (int i = 0; i < 4; i++) {
        int ff = t + i * 512;
        int rr = ff >> 4, c4 = ff & 15;
        int row = row0 + rr;
        rx[i] = (row < N_NODES) ? *(const float4*)&g.x[(size_t)row * FIN + c4 * 4]
                                : make_float4(0.f, 0.f, 0.f, 0.f);
    }
    for (int c = 0; c < 8; c++) {
#pragma unroll
        for (int i = 0; i < 4; i++) {
            int ff = t + i * 512;
            int rr = ff >> 4, c4 = ff & 15;
            ushort4 s4;
            s4.x = f2bf(rx[i].x); s4.y = f2bf(rx[i].y);
            s4.z = f2bf(rx[i].z); s4.w = f2bf(rx[i].w);
            *(ushort4*)&As[rr * 72 + c4 * 4] = s4;
        }
        __syncthreads();
        if (c < 7) {
            int kb = (c + 1) * 64;
#pragma unroll
            for (int i = 0; i < 4; i++) {
                int ff = t + i * 512;
                int rr = ff >> 4, c4 = ff & 15;
                int row = row0 + rr;
                rx[i] = (row < N_NODES)
                            ? *(const float4*)&g.x[(size_t)row * FIN + kb + c4 * 4]
                            : make_float4(0.f, 0.f, 0.f, 0.f);
            }
        }
        int kb = c * 64;
#pragma unroll
        for (int ks = 0; ks < 2; ks++) {
            bf16x8 af, bfv[5];
            af = *(const bf16x8*)&As[(wv * 16 + l16) * 72 + ks * 32 + quad * 8];
#pragma unroll
            for (int ni = 0; ni < 5; ni++) {
                int n = ni * 16 + l16;
                bfv[ni] = *(const bf16x8*)&W1t[n * FIN + kb + ks * 32 + quad * 8];
            }
#pragma unroll
            for (int ni = 0; ni < 5; ni++)
                acc[ni] = __builtin_amdgcn_mfma_f32_16x16x32_bf16(af, bfv[ni], acc[ni], 0, 0, 0);
        }
        __syncthreads();
    }
#pragma unroll
    for (int ni = 0; ni < 5; ni++)
#pragma unroll
        for (int r = 0; r < 4; r++) {
            int row = row0 + wv * 16 + quad * 4 + r;
            if (row >= N_NODES) continue;
            int col = ni * 16 + l16;
            float v = acc[ni][r];
            if (col < 64)       h1b[(size_t)row * 64 + col] = f2bf(v);
            else if (col < 72)  as1[row * 8 + (col - 64)] = v;
            else                ad1[row * 8 + (col - 72)] = v;
        }
}

// ================= P5: gemm1 (front 3/4 of blocks) || scatter (back 1/4) =================
__device__ void phase5(const GArgs& g) {
    WS_PTRS(g.ws);
    __shared__ unsigned short As[128 * 72];
    int nb = gridDim.x;
    int nscat = nb >> 2; if (nscat < 1) nscat = 1;
    int nbg = nb - nscat;
    if ((int)blockIdx.x < nbg) {
        for (int tile = blockIdx.x; tile < GTILES; tile += nbg)
            gemm1_tile(g, As, tile * 128);
    } else {
        const int t = threadIdx.x;
        for (int e = ((int)blockIdx.x - nbg) * BLOCK_T + t; e < ETOT; e += nscat * BLOCK_T) {
            int src, dst;
            if (e < N_EDGES) { src = g.ei[e]; dst = g.ei[N_EDGES + e]; }
            else             { src = dst = e - N_EDGES; }
            csr_src[row_ptr[dst] + ord[e]] = src;   // unique: rank from P1
        }
    }
}

// ================= P6: layer-1 aggregate + bias + ELU -> hb =================
__device__ void phase6(const GArgs& g) {
    WS_PTRS(g.ws);
    const int t = threadIdx.x, lane = t & 63;
    const int NWV = (gridDim.x * BLOCK_T) >> 6;
    const int gw  = (blockIdx.x * BLOCK_T + t) >> 6;
    const int h = lane >> 3;
    const float blv = g.b1[lane];
    for (int dst = gw; dst < N_NODES; dst += NWV) {
        int s0 = row_ptr[dst], s1e = row_ptr[dst + 1];
        float adh = ad1[dst * 8 + h];
        float acc = 0.f, den = 0.f;
        for (int base = s0; base < s1e; base += 64) {
            int idx = base + lane;
            int sl = (idx < s1e) ? csr_src[idx] : 0;
            int cntv = min(64, s1e - base);
            int j = 0;
            for (; j + 4 <= cntv; j += 4) {
#pragma unroll
                for (int jj = 0; jj < 4; jj++) {
                    int s = __shfl(sl, j + jj);
                    float w = __expf(lrelu(as1[s * 8 + h] + adh));
                    den += w;
                    acc += w * bf2f(h1b[(size_t)s * 64 + lane]);
                }
            }
            for (; j < cntv; j++) {
                int s = __shfl(sl, j);
                float w = __expf(lrelu(as1[s * 8 + h] + adh));
                den += w;
                acc += w * bf2f(h1b[(size_t)s * 64 + lane]);
            }
        }
        float hv = acc / (den + 1e-16f) + blv;
        hv = hv > 0.f ? hv : expm1f(hv);
        hb[(size_t)dst * 64 + lane] = f2bf(hv);
    }
}

// ================= P7: gemm2 (no LDS) =================
__device__ void phase7(const GArgs& g) {
    WS_PTRS(g.ws);
    const int t = threadIdx.x, lane = t & 63, wv = t >> 6;
    const int quad = lane >> 4, l16 = lane & 15;

    bf16x8 bfrag[2][3];
#pragma unroll
    for (int ks = 0; ks < 2; ks++)
#pragma unroll
        for (int ni = 0; ni < 3; ni++)
            bfrag[ks][ni] = *(const bf16x8*)&W2t[(ni * 16 + l16) * 64 + ks * 32 + quad * 8];

    for (int tile = blockIdx.x; tile < GTILES; tile += gridDim.x) {
        int row0 = tile * 128;
        f32x4 acc2[3];
#pragma unroll
        for (int ni = 0; ni < 3; ni++) acc2[ni] = (f32x4){0.f, 0.f, 0.f, 0.f};

        int row = row0 + wv * 16 + l16;
        int rowc = row < N_NODES ? row : N_NODES - 1;   // clamp (epilogue masks)
#pragma unroll
        for (int ks = 0; ks < 2; ks++) {
            bf16x8 af = *(const bf16x8*)&hb[(size_t)rowc * 64 + ks * 32 + quad * 8];
#pragma unroll
            for (int ni = 0; ni < 3; ni++)
                acc2[ni] = __builtin_amdgcn_mfma_f32_16x16x32_bf16(af, bfrag[ks][ni], acc2[ni], 0, 0, 0);
        }
#pragma unroll
        for (int ni = 0; ni < 3; ni++)
#pragma unroll
            for (int r = 0; r < 4; r++) {
                int orow = row0 + wv * 16 + quad * 4 + r;
                if (orow >= N_NODES) continue;
                int col = ni * 16 + l16;
                float v = acc2[ni][r];
                if (col < C2)            h2b[(size_t)orow * C2 + col] = f2bf(v);
                else if (col == C2)      as2[orow] = v;
                else if (col == C2 + 1)  ad2[orow] = v;
            }
    }
}

// ================= P8: layer-2 aggregate + bias + log_softmax =================
__device__ void phase8(const GArgs& g) {
    WS_PTRS(g.ws);
    const int t = threadIdx.x, lane = t & 63;
    const int NWV = (gridDim.x * BLOCK_T) >> 6;
    const int gw  = (blockIdx.x * BLOCK_T + t) >> 6;
    const bool act = lane < C2;
    const int cl = act ? lane : 0;
    const float b2v = act ? g.b2[cl] : 0.f;
    for (int dst = gw; dst < N_NODES; dst += NWV) {
        int s0 = row_ptr[dst], s1e = row_ptr[dst + 1];
        float ad = ad2[dst];
        float acc = 0.f, den = 0.f;
        for (int base = s0; base < s1e; base += 64) {
            int idx = base + lane;
            bool vld = idx < s1e;
            int sl = vld ? csr_src[idx] : 0;
            float wl = vld ? __expf(lrelu(as2[sl] + ad)) : 0.f;
            float d = wl;
#pragma unroll
            for (int o = 32; o >= 1; o >>= 1) d += __shfl_xor(d, o, 64);
            den += d;
            int cntv = min(64, s1e - base);
            int cnt4 = (cntv + 3) & ~3;
            for (int j = 0; j < cnt4; j += 4) {
#pragma unroll
                for (int jj = 0; jj < 4; jj++) {
                    int s   = __shfl(sl, j + jj);
                    float w = __shfl(wl, j + jj);
                    float hvv = bf2f(h2b[(size_t)s * C2 + cl]);
                    if (act) acc += w * hvv;
                }
            }
        }
        float v = act ? acc / (den + 1e-16f) + b2v : -1e30f;
        float m = v;
#pragma unroll
        for (int o = 32; o >= 1; o >>= 1) m = fmaxf(m, __shfl_xor(m, o, 64));
        float ex = act ? __expf(v - m) : 0.f;
        float ssum = ex;
#pragma unroll
        for (int o = 32; o >= 1; o >>= 1) ssum += __shfl_xor(ssum, o, 64);
        if (act) g.out[(size_t)dst * C2 + lane] = v - m - logf(ssum);
    }
}

// ================= fused cooperative kernel =================
__global__ __launch_bounds__(BLOCK_T, 4) void k_fused(GArgs g) {
    cg::grid_group grid = cg::this_grid();
    phase0(g); __threadfence(); grid.sync();
    phase1(g); __threadfence(); grid.sync();
    phase2(g); __threadfence(); grid.sync();
    phase3(g); __threadfence(); grid.sync();
    phase4(g); __threadfence(); grid.sync();
    phase5(g); __threadfence(); grid.sync();
    phase6(g); __threadfence(); grid.sync();
    phase7(g); __threadfence(); grid.sync();
    phase8(g);
}

// ================= fallback: one kernel per phase (stream-ordered) =================
template <int P>
__global__ __launch_bounds__(BLOCK_T, 4) void k_phase(GArgs g) {
    if constexpr (P == 0) phase0(g);
    else if constexpr (P == 1) phase1(g);
    else if constexpr (P == 2) phase2(g);
    else if constexpr (P == 3) phase3(g);
    else if constexpr (P == 4) phase4(g);
    else if constexpr (P == 5) phase5(g);
    else if constexpr (P == 6) phase6(g);
    else if constexpr (P == 7) phase7(g);
    else if constexpr (P == 8) phase8(g);
}

extern "C" void kernel_launch(void* const* d_in, const int* in_sizes, int n_in,
                              void* d_out, int out_size, void* d_ws, size_t ws_size,
                              hipStream_t stream) {
    GArgs g;
    g.x    = (const float*)d_in[0];
    g.ei   = (const int*)d_in[1];
    g.W1   = (const float*)d_in[2];
    g.a_s1 = (const float*)d_in[3];
    g.a_d1 = (const float*)d_in[4];
    g.b1   = (const float*)d_in[5];
    g.W2   = (const float*)d_in[6];
    g.a_s2 = (const float*)d_in[7];
    g.a_d2 = (const float*)d_in[8];
    g.b2   = (const float*)d_in[9];
    g.out  = (float*)d_out;
    g.ws   = (float*)d_ws;

    static int mode = -1;       // -1 unknown, 1 cooperative, 0 fallback
    static int coopGrid = 0;
    if (mode < 0) {
        int perCU = 0;
        hipError_t e1 = hipOccupancyMaxActiveBlocksPerMultiprocessor(&perCU, k_fused, BLOCK_T, 0);
        int numCU = 0;
        hipDeviceProp_t prop;
        int dev = 0;
        if (hipGetDevice(&dev) == hipSuccess && hipGetDeviceProperties(&prop, dev) == hipSuccess)
            numCU = prop.multiProcessorCount;
        if (numCU <= 0) numCU = 256;
        coopGrid = (e1 == hipSuccess && perCU > 0) ? perCU * numCU : 0;
        if (coopGrid > 2048) coopGrid = 2048;
        mode = (coopGrid >= 64) ? 1 : 0;
    }
    if (mode == 1) {
        void* args[] = {(void*)&g};
        hipError_t e = hipLaunchCooperativeKernel((const void*)k_fused, dim3(coopGrid),
                                                  dim3(BLOCK_T), args, 0, stream);
        if (e != hipSuccess) mode = 0;   // fall through to the sequential chain
    }
    if (mode == 0) {
        k_phase<0><<<512,  BLOCK_T, 0, stream>>>(g);
        k_phase<1><<<512,  BLOCK_T, 0, stream>>>(g);
        k_phase<2><<<NCH,  BLOCK_T, 0, stream>>>(g);
        k_phase<3><<<1,    BLOCK_T, 0, stream>>>(g);
        k_phase<4><<<512,  BLOCK_T, 0, stream>>>(g);
        k_phase<5><<<784,  BLOCK_T, 0, stream>>>(g);
        k_phase<6><<<1024, BLOCK_T, 0, stream>>>(g);
        k_phase<7><<<782,  BLOCK_T, 0, stream>>>(g);
        k_phase<8><<<1024, BLOCK_T, 0, stream>>>(g);
    }
}

// Round 3
// 593.647 us; speedup vs baseline: 2.3612x; 2.3612x over previous
//
#include <hip/hip_runtime.h>
#include <cstdint>

#define N_NODES 100000
#define N_EDGES 1600000
#define ETOT    1700000   // edges + self loops
#define FIN     512
#define HD1     64        // 8 heads * 8 dims
#define C2      40
#define NEG_SLOPE 0.2f
#define SCAN_NB ((N_NODES + 1023) / 1024)   // 98

typedef __attribute__((ext_vector_type(8))) short bf16x8;
typedef __attribute__((ext_vector_type(4))) float f32x4;

__device__ __forceinline__ float lrelu(float v) { return v > 0.f ? v : NEG_SLOPE * v; }

__device__ __forceinline__ unsigned short f2bf(float f) {
    uint32_t u = __float_as_uint(f);
    u += 0x7FFF + ((u >> 16) & 1);   // round-to-nearest-even
    return (unsigned short)(u >> 16);
}
__device__ __forceinline__ float bf2f(unsigned short u) {
    return __uint_as_float(((uint32_t)u) << 16);
}

// ---------------- prep (merged) + zero deg:
// thread i: zero deg[i] (i<N); W1t[80][512] for i<40960; W2t[48][64] for next 3072
__global__ void k_prep(const float* __restrict__ W1, const float* __restrict__ a_s,
                       const float* __restrict__ a_d,
                       const float* __restrict__ W2, const float* __restrict__ att_s2,
                       const float* __restrict__ att_d2,
                       unsigned short* __restrict__ W1t, unsigned short* __restrict__ W2t,
                       int* __restrict__ deg) {
    int i = blockIdx.x * 256 + threadIdx.x;
    if (i < N_NODES) deg[i] = 0;
    if (i < 80 * 512) {
        int n = i >> 9, k = i & 511;
        float v;
        if (n < 64) {
            v = W1[k * HD1 + n];
        } else if (n < 72) {
            int h = n - 64; v = 0.f;
#pragma unroll
            for (int d = 0; d < 8; d++) v += W1[k * HD1 + h * 8 + d] * a_s[h * 8 + d];
        } else {
            int h = n - 72; v = 0.f;
#pragma unroll
            for (int d = 0; d < 8; d++) v += W1[k * HD1 + h * 8 + d] * a_d[h * 8 + d];
        }
        W1t[n * FIN + k] = f2bf(v);
    } else if (i < 80 * 512 + 48 * 64) {
        int j = i - 80 * 512;
        int n = j >> 6, k = j & 63;
        float v = 0.f;
        if (n < C2) {
            v = W2[k * C2 + n];
        } else if (n == C2) {
            for (int c = 0; c < C2; c++) v += W2[k * C2 + c] * att_s2[c];
        } else if (n == C2 + 1) {
            for (int c = 0; c < C2; c++) v += W2[k * C2 + c] * att_d2[c];
        }
        W2t[n * 64 + k] = f2bf(v);
    }
}

// ---------------- GEMM1 (MFMA bf16): [h1b | as1 | ad1] = x @ W1t^T ----------------
__global__ __launch_bounds__(256) void k_gemm1(const float* __restrict__ x,
                                               const unsigned short* __restrict__ W1t,
                                               unsigned short* __restrict__ h1b,
                                               float* __restrict__ as1,
                                               float* __restrict__ ad1) {
    __shared__ unsigned short As[128 * 72];   // chunk of x in bf16, row stride 72 (pad 8)
    const int t    = threadIdx.x;
    const int lane = t & 63, wv = t >> 6;
    const int quad = lane >> 4, l16 = lane & 15;
    const int row0 = blockIdx.x * 128;

    f32x4 acc[2][5];
#pragma unroll
    for (int mi = 0; mi < 2; mi++)
#pragma unroll
        for (int ni = 0; ni < 5; ni++) acc[mi][ni] = (f32x4){0.f, 0.f, 0.f, 0.f};

    float4 rx[8];
#pragma unroll
    for (int i = 0; i < 8; i++) {
        int ff = t + i * 256;
        int r = ff >> 4, c4 = ff & 15;
        int row = row0 + r;
        rx[i] = (row < N_NODES) ? *(const float4*)&x[(size_t)row * FIN + c4 * 4]
                                : make_float4(0.f, 0.f, 0.f, 0.f);
    }

    for (int c = 0; c < 8; c++) {
#pragma unroll
        for (int i = 0; i < 8; i++) {
            int ff = t + i * 256;
            int r = ff >> 4, c4 = ff & 15;
            ushort4 s4;
            s4.x = f2bf(rx[i].x); s4.y = f2bf(rx[i].y);
            s4.z = f2bf(rx[i].z); s4.w = f2bf(rx[i].w);
            *(ushort4*)&As[r * 72 + c4 * 4] = s4;
        }
        __syncthreads();
        if (c < 7) {
            int kb = (c + 1) * 64;
#pragma unroll
            for (int i = 0; i < 8; i++) {
                int ff = t + i * 256;
                int r = ff >> 4, c4 = ff & 15;
                int row = row0 + r;
                rx[i] = (row < N_NODES) ? *(const float4*)&x[(size_t)row * FIN + kb + c4 * 4]
                                        : make_float4(0.f, 0.f, 0.f, 0.f);
            }
        }
        int kb = c * 64;
#pragma unroll
        for (int ks = 0; ks < 2; ks++) {
            bf16x8 af[2], bfv[5];
#pragma unroll
            for (int mi = 0; mi < 2; mi++) {
                int lr = wv * 32 + mi * 16 + l16;
                af[mi] = *(const bf16x8*)&As[lr * 72 + ks * 32 + quad * 8];
            }
#pragma unroll
            for (int ni = 0; ni < 5; ni++) {
                int n = ni * 16 + l16;
                bfv[ni] = *(const bf16x8*)&W1t[n * FIN + kb + ks * 32 + quad * 8];
            }
#pragma unroll
            for (int mi = 0; mi < 2; mi++)
#pragma unroll
                for (int ni = 0; ni < 5; ni++)
                    acc[mi][ni] = __builtin_amdgcn_mfma_f32_16x16x32_bf16(
                        af[mi], bfv[ni], acc[mi][ni], 0, 0, 0);
        }
        __syncthreads();
    }
#pragma unroll
    for (int mi = 0; mi < 2; mi++)
#pragma unroll
        for (int ni = 0; ni < 5; ni++)
#pragma unroll
            for (int r = 0; r < 4; r++) {
                int row = row0 + wv * 32 + mi * 16 + quad * 4 + r;
                if (row >= N_NODES) continue;
                int col = ni * 16 + l16;
                float v = acc[mi][ni][r];
                if (col < 64)       h1b[(size_t)row * 64 + col] = f2bf(v);
                else if (col < 72)  as1[row * 8 + (col - 64)] = v;
                else                ad1[row * 8 + (col - 72)] = v;
            }
}

// ---------------- CSR build ----------------
// degree + per-edge rank in ONE atomic pass
__global__ void k_degord(const int* __restrict__ ei, int* __restrict__ deg,
                         int* __restrict__ ord) {
    int e = blockIdx.x * 256 + threadIdx.x;
    if (e >= ETOT) return;
    int dst = (e < N_EDGES) ? ei[N_EDGES + e] : e - N_EDGES;
    ord[e] = atomicAdd(&deg[dst], 1);
}

__global__ __launch_bounds__(1024) void k_bsum(const int* __restrict__ deg,
                                               int* __restrict__ bsum) {
    __shared__ int wsm[16];
    int t = threadIdx.x;
    int i = blockIdx.x * 1024 + t;
    int v = (i < N_NODES) ? deg[i] : 0;
#pragma unroll
    for (int o = 32; o >= 1; o >>= 1) v += __shfl_xor(v, o, 64);
    if ((t & 63) == 0) wsm[t >> 6] = v;
    __syncthreads();
    if (t < 16) {
        int s = wsm[t];
#pragma unroll
        for (int o = 8; o >= 1; o >>= 1) s += __shfl_xor(s, o, 16);
        if (t == 0) bsum[blockIdx.x] = s;
    }
}

__global__ __launch_bounds__(128) void k_bscan(const int* __restrict__ bsum,
                                               int* __restrict__ boff) {
    __shared__ int sh[128];
    int t = threadIdx.x;
    int v = (t < SCAN_NB) ? bsum[t] : 0;
    sh[t] = v;
    __syncthreads();
    for (int off = 1; off < 128; off <<= 1) {
        int u = (t >= off) ? sh[t - off] : 0;
        __syncthreads();
        sh[t] += u;
        __syncthreads();
    }
    boff[t] = sh[t] - v;   // exclusive
}

__global__ __launch_bounds__(1024) void k_scan3(const int* __restrict__ deg,
                                                const int* __restrict__ boff,
                                                int* __restrict__ row_ptr) {
    __shared__ int sh[1024];
    int t = threadIdx.x;
    int i = blockIdx.x * 1024 + t;
    int v = (i < N_NODES) ? deg[i] : 0;
    sh[t] = v;
    __syncthreads();
    for (int off = 1; off < 1024; off <<= 1) {
        int u = (t >= off) ? sh[t - off] : 0;
        __syncthreads();
        sh[t] += u;
        __syncthreads();
    }
    int base = boff[blockIdx.x];
    if (i < N_NODES) row_ptr[i] = base + sh[t] - v;
    if (i == N_NODES - 1) row_ptr[N_NODES] = base + sh[t];
}

// scatter with precomputed rank — no atomics
__global__ void k_scatter(const int* __restrict__ ei, const int* __restrict__ row_ptr,
                          const int* __restrict__ ord, int* __restrict__ csr_src) {
    int e = blockIdx.x * 256 + threadIdx.x;
    if (e >= ETOT) return;
    int src, dst;
    if (e < N_EDGES) { src = ei[e]; dst = ei[N_EDGES + e]; }
    else             { src = dst = e - N_EDGES; }
    csr_src[row_ptr[dst] + ord[e]] = src;
}

// ---------------- layer 1: gather-aggregate + bias + ELU -> hb (bf16) ----------------
// one wave per dst; lane = (edge-slot g = lane>>3, head i8 = lane&7)
// 8 edges in flight per step: lane loads 16B (head i8's 8 dims) of edge g's row.
__global__ __launch_bounds__(256) void k_agg1(
    const unsigned short* __restrict__ h1b,
    const float* __restrict__ as1, const float* __restrict__ ad1,
    const int* __restrict__ row_ptr, const int* __restrict__ csr_src,
    const float* __restrict__ b1, unsigned short* __restrict__ hb) {
    int t = threadIdx.x, wv = t >> 6, lane = t & 63;
    int dst = blockIdx.x * 4 + wv;
    if (dst >= N_NODES) return;
    int g = lane >> 3, i8 = lane & 7;
    int s0 = row_ptr[dst], s1e = row_ptr[dst + 1];
    float adh = ad1[dst * 8 + i8];
    float den = 0.f;
    float facc[8];
#pragma unroll
    for (int d = 0; d < 8; d++) facc[d] = 0.f;

    for (int base = s0; base < s1e; base += 64) {
        int idx = base + lane;
        int sl = (idx < s1e) ? csr_src[idx] : 0;
        int cnt = min(64, s1e - base);
        for (int j = 0; j < cnt; j += 8) {
            int s = __shfl(sl, j + g);                     // edge (j+g)'s src
            bool vld = (j + g) < cnt;
            float w = vld ? __expf(lrelu(as1[s * 8 + i8] + adh)) : 0.f;
            den += w;
            bf16x8 hrow = *(const bf16x8*)&h1b[(size_t)s * 64 + i8 * 8];
#pragma unroll
            for (int d = 0; d < 8; d++)
                facc[d] += w * bf2f((unsigned short)hrow[d]);
        }
    }
    // reduce across edge-slots g (lane bits 3..5)
#pragma unroll
    for (int o = 8; o <= 32; o <<= 1) {
        den += __shfl_xor(den, o, 64);
#pragma unroll
        for (int d = 0; d < 8; d++) facc[d] += __shfl_xor(facc[d], o, 64);
    }
    float rden = 1.f / (den + 1e-16f);
    float4 b1lo = *(const float4*)&b1[i8 * 8];
    float4 b1hi = *(const float4*)&b1[i8 * 8 + 4];
    float bb[8] = {b1lo.x, b1lo.y, b1lo.z, b1lo.w, b1hi.x, b1hi.y, b1hi.z, b1hi.w};
    bf16x8 pk;
#pragma unroll
    for (int d = 0; d < 8; d++) {
        float hv = facc[d] * rden + bb[d];
        hv = hv > 0.f ? hv : expm1f(hv);
        pk[d] = (short)f2bf(hv);
    }
    if (g == 0) *(bf16x8*)&hb[(size_t)dst * 64 + i8 * 8] = pk;
}

// ---------------- GEMM2 (MFMA bf16): [h2b | as2 | ad2] = hb @ W2t^T ----------------
__global__ __launch_bounds__(256) void k_gemm2(const unsigned short* __restrict__ hb,
                                               const unsigned short* __restrict__ W2t,
                                               unsigned short* __restrict__ h2b,
                                               float* __restrict__ as2,
                                               float* __restrict__ ad2) {
    const int t = threadIdx.x;
    const int lane = t & 63, wv = t >> 6;
    const int quad = lane >> 4, l16 = lane & 15;
    const int row0 = blockIdx.x * 128;

    f32x4 acc[2][3];
#pragma unroll
    for (int mi = 0; mi < 2; mi++)
#pragma unroll
        for (int ni = 0; ni < 3; ni++) acc[mi][ni] = (f32x4){0.f, 0.f, 0.f, 0.f};

    bf16x8 bfrag[2][3];
#pragma unroll
    for (int ks = 0; ks < 2; ks++)
#pragma unroll
        for (int ni = 0; ni < 3; ni++)
            bfrag[ks][ni] = *(const bf16x8*)&W2t[(ni * 16 + l16) * 64 + ks * 32 + quad * 8];

#pragma unroll
    for (int mi = 0; mi < 2; mi++) {
        int row = row0 + wv * 32 + mi * 16 + l16;
        int rowc = row < N_NODES ? row : N_NODES - 1;   // clamp (epilogue masks)
#pragma unroll
        for (int ks = 0; ks < 2; ks++) {
            bf16x8 af = *(const bf16x8*)&hb[(size_t)rowc * 64 + ks * 32 + quad * 8];
#pragma unroll
            for (int ni = 0; ni < 3; ni++)
                acc[mi][ni] = __builtin_amdgcn_mfma_f32_16x16x32_bf16(
                    af, bfrag[ks][ni], acc[mi][ni], 0, 0, 0);
        }
    }
#pragma unroll
    for (int mi = 0; mi < 2; mi++)
#pragma unroll
        for (int ni = 0; ni < 3; ni++)
#pragma unroll
            for (int r = 0; r < 4; r++) {
                int row = row0 + wv * 32 + mi * 16 + quad * 4 + r;
                if (row >= N_NODES) continue;
                int col = ni * 16 + l16;
                float v = acc[mi][ni][r];
                if (col < C2)            h2b[(size_t)row * C2 + col] = f2bf(v);
                else if (col == C2)      as2[row] = v;
                else if (col == C2 + 1)  ad2[row] = v;
            }
}

// ---------------- layer 2: gather-aggregate + bias + log_softmax ----------------
// one wave per dst; lane = (edge-slot g = lane>>3, chunk i8 = lane&7); chunks 0..4 active
__global__ __launch_bounds__(256) void k_agg2(
    const unsigned short* __restrict__ h2b,
    const float* __restrict__ as2, const float* __restrict__ ad2,
    const int* __restrict__ row_ptr, const int* __restrict__ csr_src,
    const float* __restrict__ b2, float* __restrict__ out) {
    int t = threadIdx.x, wv = t >> 6, lane = t & 63;
    int dst = blockIdx.x * 4 + wv;
    if (dst >= N_NODES) return;
    int g = lane >> 3, i8 = lane & 7;
    bool act = i8 < 5;
    int off = act ? i8 * 8 : 0;
    int s0 = row_ptr[dst], s1e = row_ptr[dst + 1];
    float ad = ad2[dst];
    float denp = 0.f;
    float facc[8];
#pragma unroll
    for (int d = 0; d < 8; d++) facc[d] = 0.f;

    for (int base = s0; base < s1e; base += 64) {
        int idx = base + lane;
        int sl = (idx < s1e) ? csr_src[idx] : 0;
        int cnt = min(64, s1e - base);
        for (int j = 0; j < cnt; j += 8) {
            int s = __shfl(sl, j + g);
            bool vld = (j + g) < cnt;
            float wf = vld ? __expf(lrelu(as2[s] + ad)) : 0.f;
            if (i8 == 0) denp += wf;                       // each edge counted once
            float w = act ? wf : 0.f;
            bf16x8 hrow = *(const bf16x8*)&h2b[(size_t)s * C2 + off];
#pragma unroll
            for (int d = 0; d < 8; d++)
                facc[d] += w * bf2f((unsigned short)hrow[d]);
        }
    }
    // facc: reduce across edge-slots g (bits 3..5)
#pragma unroll
    for (int o = 8; o <= 32; o <<= 1)
#pragma unroll
        for (int d = 0; d < 8; d++) facc[d] += __shfl_xor(facc[d], o, 64);
    // den: full 64-lane butterfly of the i8==0 partials
    float den = denp;
#pragma unroll
    for (int o = 32; o >= 1; o >>= 1) den += __shfl_xor(den, o, 64);
    float rden = 1.f / (den + 1e-16f);

    float vch[8];
    float mx = -1e30f;
#pragma unroll
    for (int d = 0; d < 8; d++) {
        vch[d] = act ? facc[d] * rden + b2[off + d] : -1e30f;
        mx = fmaxf(mx, vch[d]);
    }
#pragma unroll
    for (int o = 1; o <= 4; o <<= 1) mx = fmaxf(mx, __shfl_xor(mx, o, 64));
    float es = 0.f;
#pragma unroll
    for (int d = 0; d < 8; d++) es += act ? __expf(vch[d] - mx) : 0.f;
#pragma unroll
    for (int o = 1; o <= 4; o <<= 1) es += __shfl_xor(es, o, 64);
    float lg = logf(es);
    if (g == 0 && act) {
        float4 o0 = {vch[0] - mx - lg, vch[1] - mx - lg, vch[2] - mx - lg, vch[3] - mx - lg};
        float4 o1 = {vch[4] - mx - lg, vch[5] - mx - lg, vch[6] - mx - lg, vch[7] - mx - lg};
        *(float4*)&out[(size_t)dst * C2 + i8 * 8]     = o0;
        *(float4*)&out[(size_t)dst * C2 + i8 * 8 + 4] = o1;
    }
}

extern "C" void kernel_launch(void* const* d_in, const int* in_sizes, int n_in,
                              void* d_out, int out_size, void* d_ws, size_t ws_size,
                              hipStream_t stream) {
    const float* x     = (const float*)d_in[0];
    const int*   ei    = (const int*)d_in[1];
    const float* W1    = (const float*)d_in[2];
    const float* at_s1 = (const float*)d_in[3];
    const float* at_d1 = (const float*)d_in[4];
    const float* b1    = (const float*)d_in[5];
    const float* W2    = (const float*)d_in[6];
    const float* at_s2 = (const float*)d_in[7];
    const float* at_d2 = (const float*)d_in[8];
    const float* b2    = (const float*)d_in[9];
    float* out = (float*)d_out;
    float* ws  = (float*)d_ws;

    // workspace layout (float-element offsets) — NON-OVERLAPPING:
    unsigned short* h1b = (unsigned short*)ws;                 // [0, 3.2M)  N*64 bf16
    float* as1 = ws + 3200000;                                 // [3.2M,4.0M)
    float* ad1 = ws + 4000000;                                 // [4.0M,4.8M)
    unsigned short* hb  = (unsigned short*)(ws + 4800000);     // [4.8M,8.0M) N*64 bf16
    unsigned short* h2b = (unsigned short*)(ws + 8000000);     // [8.0M,10.0M) N*40 bf16
    float* as2 = ws + 10000000;                                // [10.0M,10.1M)
    float* ad2 = ws + 10100000;                                // [10.1M,10.2M)
    unsigned short* W1t = (unsigned short*)(ws + 10200000);    // 40960 ush
    unsigned short* W2t = (unsigned short*)(ws + 10250000);    // 3072 ush
    int* row_ptr = (int*)(ws + 10300000);                      // N+1
    int* deg     = (int*)(ws + 10410000);                      // N
    int* csr_src = (int*)(ws + 10630000);                      // ETOT -> ends 12.33M
    int* bsum    = (int*)(ws + 12340000);                      // 98
    int* boff    = (int*)(ws + 12350000);                      // 128
    int* ord     = (int*)(ws + 13000000);                      // ETOT -> ends 14.7M

    k_prep<<<391, 256, 0, stream>>>(W1, at_s1, at_d1, W2, at_s2, at_d2, W1t, W2t, deg);
    k_degord<<<(ETOT + 255) / 256, 256, 0, stream>>>(ei, deg, ord);
    k_bsum<<<SCAN_NB, 1024, 0, stream>>>(deg, bsum);
    k_bscan<<<1, 128, 0, stream>>>(bsum, boff);
    k_scan3<<<SCAN_NB, 1024, 0, stream>>>(deg, boff, row_ptr);
    k_scatter<<<(ETOT + 255) / 256, 256, 0, stream>>>(ei, row_ptr, ord, csr_src);
    k_gemm1<<<(N_NODES + 127) / 128, 256, 0, stream>>>(x, W1t, h1b, as1, ad1);
    k_agg1<<<(N_NODES + 3) / 4, 256, 0, stream>>>(h1b, as1, ad1, row_ptr, csr_src, b1, hb);
    k_gemm2<<<(N_NODES + 127) / 128, 256, 0, stream>>>(hb, W2t, h2b, as2, ad2);
    k_agg2<<<(N_NODES + 3) / 4, 256, 0, stream>>>(h2b, as2, ad2, row_ptr, csr_src, b2, out);
}

// Round 4
// 565.686 us; speedup vs baseline: 2.4779x; 1.0494x over previous
//
#include <hip/hip_runtime.h>
#include <cstdint>

#define N_NODES 100000
#define N_EDGES 1600000
#define ETOT    1700000   // edges + self loops
#define FIN     512
#define HD1     64        // 8 heads * 8 dims
#define C2      40
#define NEG_SLOPE 0.2f
#define GEMM1_NB 782      // ceil(N_NODES/128)
#define DEG_NB   832      // extra blocks for degord in the merged kernel
#define SCAN_NB2 98       // ceil(N_NODES/1024), all-resident lookback scan

typedef __attribute__((ext_vector_type(8))) short bf16x8;
typedef __attribute__((ext_vector_type(4))) float f32x4;

__device__ __forceinline__ float lrelu(float v) { return v > 0.f ? v : NEG_SLOPE * v; }

__device__ __forceinline__ unsigned short f2bf(float f) {
    uint32_t u = __float_as_uint(f);
    u += 0x7FFF + ((u >> 16) & 1);   // round-to-nearest-even
    return (unsigned short)(u >> 16);
}
__device__ __forceinline__ float bf2f(unsigned short u) {
    return __uint_as_float(((uint32_t)u) << 16);
}

// ---------------- prep (merged) + zero deg + zero scan flags ----------------
__global__ void k_prep(const float* __restrict__ W1, const float* __restrict__ a_s,
                       const float* __restrict__ a_d,
                       const float* __restrict__ W2, const float* __restrict__ att_s2,
                       const float* __restrict__ att_d2,
                       unsigned short* __restrict__ W1t, unsigned short* __restrict__ W2t,
                       int* __restrict__ deg, unsigned int* __restrict__ flags) {
    int i = blockIdx.x * 256 + threadIdx.x;
    if (i < N_NODES) deg[i] = 0;
    if (i < 128) flags[i] = 0u;
    if (i < 80 * 512) {
        int n = i >> 9, k = i & 511;
        float v;
        if (n < 64) {
            v = W1[k * HD1 + n];
        } else if (n < 72) {
            int h = n - 64; v = 0.f;
#pragma unroll
            for (int d = 0; d < 8; d++) v += W1[k * HD1 + h * 8 + d] * a_s[h * 8 + d];
        } else {
            int h = n - 72; v = 0.f;
#pragma unroll
            for (int d = 0; d < 8; d++) v += W1[k * HD1 + h * 8 + d] * a_d[h * 8 + d];
        }
        W1t[n * FIN + k] = f2bf(v);
    } else if (i < 80 * 512 + 48 * 64) {
        int j = i - 80 * 512;
        int n = j >> 6, k = j & 63;
        float v = 0.f;
        if (n < C2) {
            v = W2[k * C2 + n];
        } else if (n == C2) {
            for (int c = 0; c < C2; c++) v += W2[k * C2 + c] * att_s2[c];
        } else if (n == C2 + 1) {
            for (int c = 0; c < C2; c++) v += W2[k * C2 + c] * att_d2[c];
        }
        W2t[n * 64 + k] = f2bf(v);
    }
}

// ---------------- merged: GEMM1 (blocks < GEMM1_NB) || degord (rest) ----------------
// Both depend only on k_prep; BW-bound MFMA work overlaps atomic-latency work.
__global__ __launch_bounds__(256) void k_g1deg(const float* __restrict__ x,
                                               const unsigned short* __restrict__ W1t,
                                               unsigned short* __restrict__ h1b,
                                               float* __restrict__ as1,
                                               float* __restrict__ ad1,
                                               const int* __restrict__ ei,
                                               int* __restrict__ deg,
                                               int* __restrict__ ord) {
    __shared__ unsigned short As[128 * 72];   // chunk of x in bf16, row stride 72 (pad 8)
    const int t = threadIdx.x;
    if (blockIdx.x >= GEMM1_NB) {
        // ---- degord: degree + per-edge rank in one atomic pass ----
        for (int e = ((int)blockIdx.x - GEMM1_NB) * 256 + t; e < ETOT; e += DEG_NB * 256) {
            int dst = (e < N_EDGES) ? ei[N_EDGES + e] : e - N_EDGES;
            ord[e] = atomicAdd(&deg[dst], 1);
        }
        return;
    }
    const int lane = t & 63, wv = t >> 6;
    const int quad = lane >> 4, l16 = lane & 15;
    const int row0 = blockIdx.x * 128;

    f32x4 acc[2][5];
#pragma unroll
    for (int mi = 0; mi < 2; mi++)
#pragma unroll
        for (int ni = 0; ni < 5; ni++) acc[mi][ni] = (f32x4){0.f, 0.f, 0.f, 0.f};

    float4 rx[8];
#pragma unroll
    for (int i = 0; i < 8; i++) {
        int ff = t + i * 256;
        int r = ff >> 4, c4 = ff & 15;
        int row = row0 + r;
        rx[i] = (row < N_NODES) ? *(const float4*)&x[(size_t)row * FIN + c4 * 4]
                                : make_float4(0.f, 0.f, 0.f, 0.f);
    }

    for (int c = 0; c < 8; c++) {
#pragma unroll
        for (int i = 0; i < 8; i++) {
            int ff = t + i * 256;
            int r = ff >> 4, c4 = ff & 15;
            ushort4 s4;
            s4.x = f2bf(rx[i].x); s4.y = f2bf(rx[i].y);
            s4.z = f2bf(rx[i].z); s4.w = f2bf(rx[i].w);
            *(ushort4*)&As[r * 72 + c4 * 4] = s4;
        }
        __syncthreads();
        if (c < 7) {
            int kb = (c + 1) * 64;
#pragma unroll
            for (int i = 0; i < 8; i++) {
                int ff = t + i * 256;
                int r = ff >> 4, c4 = ff & 15;
                int row = row0 + r;
                rx[i] = (row < N_NODES) ? *(const float4*)&x[(size_t)row * FIN + kb + c4 * 4]
                                        : make_float4(0.f, 0.f, 0.f, 0.f);
            }
        }
        int kb = c * 64;
#pragma unroll
        for (int ks = 0; ks < 2; ks++) {
            bf16x8 af[2], bfv[5];
#pragma unroll
            for (int mi = 0; mi < 2; mi++) {
                int lr = wv * 32 + mi * 16 + l16;
                af[mi] = *(const bf16x8*)&As[lr * 72 + ks * 32 + quad * 8];
            }
#pragma unroll
            for (int ni = 0; ni < 5; ni++) {
                int n = ni * 16 + l16;
                bfv[ni] = *(const bf16x8*)&W1t[n * FIN + kb + ks * 32 + quad * 8];
            }
#pragma unroll
            for (int mi = 0; mi < 2; mi++)
#pragma unroll
                for (int ni = 0; ni < 5; ni++)
                    acc[mi][ni] = __builtin_amdgcn_mfma_f32_16x16x32_bf16(
                        af[mi], bfv[ni], acc[mi][ni], 0, 0, 0);
        }
        __syncthreads();
    }
#pragma unroll
    for (int mi = 0; mi < 2; mi++)
#pragma unroll
        for (int ni = 0; ni < 5; ni++)
#pragma unroll
            for (int r = 0; r < 4; r++) {
                int row = row0 + wv * 32 + mi * 16 + quad * 4 + r;
                if (row >= N_NODES) continue;
                int col = ni * 16 + l16;
                float v = acc[mi][ni][r];
                if (col < 64)       h1b[(size_t)row * 64 + col] = f2bf(v);
                else if (col < 72)  as1[row * 8 + (col - 64)] = v;
                else                ad1[row * 8 + (col - 72)] = v;
            }
}

// ---------------- single-kernel decoupled-lookback scan: deg -> row_ptr (exclusive) ------
// 98 blocks <= 256 CUs -> all blocks co-resident -> predecessor spin always terminates.
__global__ __launch_bounds__(1024) void k_scan_lb(const int* __restrict__ deg,
                                                  int* __restrict__ row_ptr,
                                                  int* __restrict__ aggr,
                                                  int* __restrict__ incl,
                                                  unsigned int* __restrict__ flags) {
    __shared__ int sh[1024];
    __shared__ int shbase;
    const int t = threadIdx.x, b = blockIdx.x;
    const int i = b * 1024 + t;
    int v = (i < N_NODES) ? deg[i] : 0;
    sh[t] = v;
    __syncthreads();
    for (int off = 1; off < 1024; off <<= 1) {
        int u = (t >= off) ? sh[t - off] : 0;
        __syncthreads();
        sh[t] += u;
        __syncthreads();
    }
    if (t == 0) {
        int total = sh[1023];
        int run = 0;
        if (b == 0) {
            __hip_atomic_store(&incl[0], total, __ATOMIC_RELEASE, __HIP_MEMORY_SCOPE_AGENT);
            __hip_atomic_store(&flags[0], 2u, __ATOMIC_RELEASE, __HIP_MEMORY_SCOPE_AGENT);
        } else {
            __hip_atomic_store(&aggr[b], total, __ATOMIC_RELEASE, __HIP_MEMORY_SCOPE_AGENT);
            __hip_atomic_store(&flags[b], 1u, __ATOMIC_RELEASE, __HIP_MEMORY_SCOPE_AGENT);
            int p = b - 1;
            while (true) {
                unsigned int f = __hip_atomic_load(&flags[p], __ATOMIC_ACQUIRE,
                                                   __HIP_MEMORY_SCOPE_AGENT);
                if (f == 2u) {
                    run += __hip_atomic_load(&incl[p], __ATOMIC_ACQUIRE,
                                             __HIP_MEMORY_SCOPE_AGENT);
                    break;
                } else if (f == 1u) {
                    run += __hip_atomic_load(&aggr[p], __ATOMIC_ACQUIRE,
                                             __HIP_MEMORY_SCOPE_AGENT);
                    --p;
                }
            }
            __hip_atomic_store(&incl[b], run + total, __ATOMIC_RELEASE,
                               __HIP_MEMORY_SCOPE_AGENT);
            __hip_atomic_store(&flags[b], 2u, __ATOMIC_RELEASE, __HIP_MEMORY_SCOPE_AGENT);
        }
        shbase = run;
        if (b == 0) row_ptr[N_NODES] = ETOT;   // scan total is a compile-time constant
    }
    __syncthreads();
    int base = shbase;
    if (i < N_NODES) row_ptr[i] = base + sh[t] - v;
}

// scatter with precomputed rank — no atomics
__global__ void k_scatter(const int* __restrict__ ei, const int* __restrict__ row_ptr,
                          const int* __restrict__ ord, int* __restrict__ csr_src) {
    int e = blockIdx.x * 256 + threadIdx.x;
    if (e >= ETOT) return;
    int src, dst;
    if (e < N_EDGES) { src = ei[e]; dst = ei[N_EDGES + e]; }
    else             { src = dst = e - N_EDGES; }
    csr_src[row_ptr[dst] + ord[e]] = src;
}

// ---------------- layer 1: gather-aggregate + bias + ELU -> hb (bf16) ----------------
// one wave per dst; lane = (edge-slot g = lane>>3, head i8 = lane&7)
// 16 edges in flight per step (two independent 8-edge groups) for 2x memory parallelism.
__global__ __launch_bounds__(256) void k_agg1(
    const unsigned short* __restrict__ h1b,
    const float* __restrict__ as1, const float* __restrict__ ad1,
    const int* __restrict__ row_ptr, const int* __restrict__ csr_src,
    const float* __restrict__ b1, unsigned short* __restrict__ hb) {
    int t = threadIdx.x, wv = t >> 6, lane = t & 63;
    int dst = blockIdx.x * 4 + wv;
    if (dst >= N_NODES) return;
    int g = lane >> 3, i8 = lane & 7;
    int s0 = row_ptr[dst], s1e = row_ptr[dst + 1];
    float adh = ad1[dst * 8 + i8];
    float den = 0.f;
    float facc[8];
#pragma unroll
    for (int d = 0; d < 8; d++) facc[d] = 0.f;

    for (int base = s0; base < s1e; base += 64) {
        int idx = base + lane;
        int sl = (idx < s1e) ? csr_src[idx] : 0;
        int cnt = min(64, s1e - base);
        for (int j = 0; j < cnt; j += 16) {
            int sA = __shfl(sl, j + g);
            int sB = __shfl(sl, j + 8 + g);
            bool vA = (j + g) < cnt, vB = (j + 8 + g) < cnt;
            // issue both gathers before consuming either
            bf16x8 rA = *(const bf16x8*)&h1b[(size_t)sA * 64 + i8 * 8];
            bf16x8 rB = *(const bf16x8*)&h1b[(size_t)sB * 64 + i8 * 8];
            float aA = as1[sA * 8 + i8];
            float aB = as1[sB * 8 + i8];
            float wA = vA ? __expf(lrelu(aA + adh)) : 0.f;
            float wB = vB ? __expf(lrelu(aB + adh)) : 0.f;
            den += wA + wB;
#pragma unroll
            for (int d = 0; d < 8; d++)
                facc[d] += wA * bf2f((unsigned short)rA[d]) +
                           wB * bf2f((unsigned short)rB[d]);
        }
    }
    // reduce across edge-slots g (lane bits 3..5)
#pragma unroll
    for (int o = 8; o <= 32; o <<= 1) {
        den += __shfl_xor(den, o, 64);
#pragma unroll
        for (int d = 0; d < 8; d++) facc[d] += __shfl_xor(facc[d], o, 64);
    }
    float rden = 1.f / (den + 1e-16f);
    float4 b1lo = *(const float4*)&b1[i8 * 8];
    float4 b1hi = *(const float4*)&b1[i8 * 8 + 4];
    float bb[8] = {b1lo.x, b1lo.y, b1lo.z, b1lo.w, b1hi.x, b1hi.y, b1hi.z, b1hi.w};
    bf16x8 pk;
#pragma unroll
    for (int d = 0; d < 8; d++) {
        float hv = facc[d] * rden + bb[d];
        hv = hv > 0.f ? hv : expm1f(hv);
        pk[d] = (short)f2bf(hv);
    }
    if (g == 0) *(bf16x8*)&hb[(size_t)dst * 64 + i8 * 8] = pk;
}

// ---------------- GEMM2 (MFMA bf16): [h2b | as2 | ad2] = hb @ W2t^T ----------------
__global__ __launch_bounds__(256) void k_gemm2(const unsigned short* __restrict__ hb,
                                               const unsigned short* __restrict__ W2t,
                                               unsigned short* __restrict__ h2b,
                                               float* __restrict__ as2,
                                               float* __restrict__ ad2) {
    const int t = threadIdx.x;
    const int lane = t & 63, wv = t >> 6;
    const int quad = lane >> 4, l16 = lane & 15;
    const int row0 = blockIdx.x * 128;

    f32x4 acc[2][3];
#pragma unroll
    for (int mi = 0; mi < 2; mi++)
#pragma unroll
        for (int ni = 0; ni < 3; ni++) acc[mi][ni] = (f32x4){0.f, 0.f, 0.f, 0.f};

    bf16x8 bfrag[2][3];
#pragma unroll
    for (int ks = 0; ks < 2; ks++)
#pragma unroll
        for (int ni = 0; ni < 3; ni++)
            bfrag[ks][ni] = *(const bf16x8*)&W2t[(ni * 16 + l16) * 64 + ks * 32 + quad * 8];

#pragma unroll
    for (int mi = 0; mi < 2; mi++) {
        int row = row0 + wv * 32 + mi * 16 + l16;
        int rowc = row < N_NODES ? row : N_NODES - 1;   // clamp (epilogue masks)
#pragma unroll
        for (int ks = 0; ks < 2; ks++) {
            bf16x8 af = *(const bf16x8*)&hb[(size_t)rowc * 64 + ks * 32 + quad * 8];
#pragma unroll
            for (int ni = 0; ni < 3; ni++)
                acc[mi][ni] = __builtin_amdgcn_mfma_f32_16x16x32_bf16(
                    af, bfrag[ks][ni], acc[mi][ni], 0, 0, 0);
        }
    }
#pragma unroll
    for (int mi = 0; mi < 2; mi++)
#pragma unroll
        for (int ni = 0; ni < 3; ni++)
#pragma unroll
            for (int r = 0; r < 4; r++) {
                int row = row0 + wv * 32 + mi * 16 + quad * 4 + r;
                if (row >= N_NODES) continue;
                int col = ni * 16 + l16;
                float v = acc[mi][ni][r];
                if (col < C2)            h2b[(size_t)row * C2 + col] = f2bf(v);
                else if (col == C2)      as2[row] = v;
                else if (col == C2 + 1)  ad2[row] = v;
            }
}

// ---------------- layer 2: gather-aggregate + bias + log_softmax ----------------
// one wave per dst; lane = (edge-slot g = lane>>3, chunk i8 = lane&7); chunks 0..4 active
// 16 edges per step (two independent 8-edge groups).
__global__ __launch_bounds__(256) void k_agg2(
    const unsigned short* __restrict__ h2b,
    const float* __restrict__ as2, const float* __restrict__ ad2,
    const int* __restrict__ row_ptr, const int* __restrict__ csr_src,
    const float* __restrict__ b2, float* __restrict__ out) {
    int t = threadIdx.x, wv = t >> 6, lane = t & 63;
    int dst = blockIdx.x * 4 + wv;
    if (dst >= N_NODES) return;
    int g = lane >> 3, i8 = lane & 7;
    bool act = i8 < 5;
    int off = act ? i8 * 8 : 0;
    int s0 = row_ptr[dst], s1e = row_ptr[dst + 1];
    float ad = ad2[dst];
    float denp = 0.f;
    float facc[8];
#pragma unroll
    for (int d = 0; d < 8; d++) facc[d] = 0.f;

    for (int base = s0; base < s1e; base += 64) {
        int idx = base + lane;
        int sl = (idx < s1e) ? csr_src[idx] : 0;
        int cnt = min(64, s1e - base);
        for (int j = 0; j < cnt; j += 16) {
            int sA = __shfl(sl, j + g);
            int sB = __shfl(sl, j + 8 + g);
            bool vA = (j + g) < cnt, vB = (j + 8 + g) < cnt;
            bf16x8 rA = *(const bf16x8*)&h2b[(size_t)sA * C2 + off];
            bf16x8 rB = *(const bf16x8*)&h2b[(size_t)sB * C2 + off];
            float aA = as2[sA];
            float aB = as2[sB];
            float wfA = vA ? __expf(lrelu(aA + ad)) : 0.f;
            float wfB = vB ? __expf(lrelu(aB + ad)) : 0.f;
            if (i8 == 0) denp += wfA + wfB;                // each edge counted once
            float wA = act ? wfA : 0.f;
            float wB = act ? wfB : 0.f;
#pragma unroll
            for (int d = 0; d < 8; d++)
                facc[d] += wA * bf2f((unsigned short)rA[d]) +
                           wB * bf2f((unsigned short)rB[d]);
        }
    }
    // facc: reduce across edge-slots g (bits 3..5)
#pragma unroll
    for (int o = 8; o <= 32; o <<= 1)
#pragma unroll
        for (int d = 0; d < 8; d++) facc[d] += __shfl_xor(facc[d], o, 64);
    // den: full 64-lane butterfly of the i8==0 partials
    float den = denp;
#pragma unroll
    for (int o = 32; o >= 1; o >>= 1) den += __shfl_xor(den, o, 64);
    float rden = 1.f / (den + 1e-16f);

    float vch[8];
    float mx = -1e30f;
#pragma unroll
    for (int d = 0; d < 8; d++) {
        vch[d] = act ? facc[d] * rden + b2[off + d] : -1e30f;
        mx = fmaxf(mx, vch[d]);
    }
#pragma unroll
    for (int o = 1; o <= 4; o <<= 1) mx = fmaxf(mx, __shfl_xor(mx, o, 64));
    float es = 0.f;
#pragma unroll
    for (int d = 0; d < 8; d++) es += act ? __expf(vch[d] - mx) : 0.f;
#pragma unroll
    for (int o = 1; o <= 4; o <<= 1) es += __shfl_xor(es, o, 64);
    float lg = logf(es);
    if (g == 0 && act) {
        float4 o0 = {vch[0] - mx - lg, vch[1] - mx - lg, vch[2] - mx - lg, vch[3] - mx - lg};
        float4 o1 = {vch[4] - mx - lg, vch[5] - mx - lg, vch[6] - mx - lg, vch[7] - mx - lg};
        *(float4*)&out[(size_t)dst * C2 + i8 * 8]     = o0;
        *(float4*)&out[(size_t)dst * C2 + i8 * 8 + 4] = o1;
    }
}

extern "C" void kernel_launch(void* const* d_in, const int* in_sizes, int n_in,
                              void* d_out, int out_size, void* d_ws, size_t ws_size,
                              hipStream_t stream) {
    const float* x     = (const float*)d_in[0];
    const int*   ei    = (const int*)d_in[1];
    const float* W1    = (const float*)d_in[2];
    const float* at_s1 = (const float*)d_in[3];
    const float* at_d1 = (const float*)d_in[4];
    const float* b1    = (const float*)d_in[5];
    const float* W2    = (const float*)d_in[6];
    const float* at_s2 = (const float*)d_in[7];
    const float* at_d2 = (const float*)d_in[8];
    const float* b2    = (const float*)d_in[9];
    float* out = (float*)d_out;
    float* ws  = (float*)d_ws;

    // workspace layout (float-element offsets) — NON-OVERLAPPING:
    unsigned short* h1b = (unsigned short*)ws;                 // [0, 3.2M)  N*64 bf16
    float* as1 = ws + 3200000;                                 // [3.2M,4.0M)
    float* ad1 = ws + 4000000;                                 // [4.0M,4.8M)
    unsigned short* hb  = (unsigned short*)(ws + 4800000);     // [4.8M,8.0M) N*64 bf16
    unsigned short* h2b = (unsigned short*)(ws + 8000000);     // [8.0M,10.0M) N*40 bf16
    float* as2 = ws + 10000000;                                // [10.0M,10.1M)
    float* ad2 = ws + 10100000;                                // [10.1M,10.2M)
    unsigned short* W1t = (unsigned short*)(ws + 10200000);    // 40960 ush
    unsigned short* W2t = (unsigned short*)(ws + 10250000);    // 3072 ush
    int* row_ptr = (int*)(ws + 10300000);                      // N+1
    int* deg     = (int*)(ws + 10410000);                      // N
    int* csr_src = (int*)(ws + 10630000);                      // ETOT -> ends 12.33M
    int* aggrA   = (int*)(ws + 12340000);                      // 98
    int* inclA   = (int*)(ws + 12350000);                      // 98
    unsigned int* flags = (unsigned int*)(ws + 12360000);      // 128
    int* ord     = (int*)(ws + 13000000);                      // ETOT -> ends 14.7M

    k_prep<<<391, 256, 0, stream>>>(W1, at_s1, at_d1, W2, at_s2, at_d2, W1t, W2t, deg, flags);
    k_g1deg<<<GEMM1_NB + DEG_NB, 256, 0, stream>>>(x, W1t, h1b, as1, ad1, ei, deg, ord);
    k_scan_lb<<<SCAN_NB2, 1024, 0, stream>>>(deg, row_ptr, aggrA, inclA, flags);
    k_scatter<<<(ETOT + 255) / 256, 256, 0, stream>>>(ei, row_ptr, ord, csr_src);
    k_agg1<<<(N_NODES + 3) / 4, 256, 0, stream>>>(h1b, as1, ad1, row_ptr, csr_src, b1, hb);
    k_gemm2<<<(N_NODES + 127) / 128, 256, 0, stream>>>(hb, W2t, h2b, as2, ad2);
    k_agg2<<<(N_NODES + 3) / 4, 256, 0, stream>>>(h2b, as2, ad2, row_ptr, csr_src, b2, out);
}